// Round 1
// baseline (101.056 us; speedup 1.0000x reference)
//
#include <hip/hip_runtime.h>

#ifndef __has_builtin
#define __has_builtin(x) 0
#endif

// Native 2^x / 1/x. Guarded so a missing builtin degrades to the HIP fast-math
// intrinsic instead of a compile failure.
#if __has_builtin(__builtin_amdgcn_exp2f)
#define FAST_EXP2(x) __builtin_amdgcn_exp2f(x)
#else
#define FAST_EXP2(x) __expf((x) * 0.69314718055994531f)
#endif
#if __has_builtin(__builtin_amdgcn_rcpf)
#define FAST_RCP(x) __builtin_amdgcn_rcpf(x)
#else
#define FAST_RCP(x) (1.0f / (x))
#endif

#define P_PTS 2048   // points per diagram (problem constant)
#define S_SAMP 128   // samples (problem constant)
#define NTH 512      // 128 samples x 4 point-quarters

// One block per diagram n.
// Phase A: 512 threads stage all 2048 points: load (x,y)+mask, pre-fold
//          (a*mid, -c*half, w), ballot-compact valid points into LDS.
// Phase C: thread (q,s) accumulates quarter q of the compacted points for
//          sample s; LDS reduction over the 4 quarters; write out[n,s].
__global__ __launch_bounds__(NTH, 2) void perslay_kernel(
    const float* __restrict__ diagrams,   // (N, P, 2) f32
    const void*  __restrict__ maskp,      // (N, P) bool (byte) OR int32 -- autodetected
    const float* __restrict__ samples,    // (S,) f32
    const float* __restrict__ theta,      // (1,)
    const float* __restrict__ constant,   // (1,)
    const float* __restrict__ power,      // (1,)
    float* __restrict__ out)              // (N, S) f32
{
    __shared__ float4 pts[P_PTS];   // compacted (a*mid, -c*half, w, _)
    __shared__ int    woff[33];     // per-(round,wave) counts -> exclusive prefix
    __shared__ float  part[NTH];    // per-quarter partial sums

    const int n    = blockIdx.x;
    const int tid  = threadIdx.x;
    const int lane = tid & 63;
    const int wid  = tid >> 6;      // 0..7

    const float th  = theta[0];
    const float cst = constant[0];
    const float pw  = power[0];
    const float c   = th * 1.4426950408889634f;   // theta * log2(e)
    const float a   = fabsf(c);
    const float sgn = (c >= 0.0f) ? 1.0f : -1.0f;

    // Mask dtype autodetect: byte-packed bool with a valid-prefix mask makes
    // word0 = 0x01010101 (>1); an int32 0/1 mask keeps all words <= 1.
    const unsigned int* mw = (const unsigned int*)maskp;
    const bool isByte = (mw[0] > 1u) | (mw[1] > 1u) | (mw[2] > 1u) | (mw[3] > 1u);

    const float2* __restrict__ dg = ((const float2*)diagrams) + (size_t)n * P_PTS;

    float4 val[4];
    int    rank[4];
    bool   valid[4];

    #pragma unroll
    for (int r = 0; r < 4; ++r) {
        const int p = r * NTH + tid;
        const float2 xy = dg[p];
        bool m;
        if (isByte) m = ((const unsigned char*)maskp)[(size_t)n * P_PTS + p] != 0;
        else        m = ((const int*)maskp)[(size_t)n * P_PTS + p] != 0;
        const float pers = xy.y - xy.x;
        const float ap   = fabsf(pers);
        float w;
        if (pw == 1.0f)      w = cst * ap;            // benchmark fast path
        else if (pw == 2.0f) w = cst * ap * ap;
        else                 w = cst * powf(ap, pw);  // general path
        valid[r] = m && (w != 0.0f);                  // zero-weight points add exactly 0
        const float mid = 0.5f * (xy.x + xy.y);
        const float hf  = 0.5f * pers;
        val[r] = make_float4(a * mid, -c * hf, w, 0.0f);
        const unsigned long long b = __ballot(valid[r] ? 1 : 0);
        if (lane == 0) woff[r * 8 + wid] = (int)__popcll(b);
        rank[r] = (int)__popcll(b & ((1ull << lane) - 1ull));
    }
    __syncthreads();

    if (tid == 0) {  // exclusive prefix over the 32 (round,wave) chunks
        int run = 0;
        #pragma unroll
        for (int j = 0; j < 32; ++j) { const int t = woff[j]; woff[j] = run; run += t; }
        woff[32] = run;
    }
    __syncthreads();

    #pragma unroll
    for (int r = 0; r < 4; ++r)
        if (valid[r]) pts[woff[r * 8 + wid] + rank[r]] = val[r];
    const int cnt = woff[32];   // written before previous barrier; safe to read here
    __syncthreads();

    // Phase C: sample s = tid&127 sweeps compacted points [i0,i1) of quarter q.
    const int   q  = tid >> 7;              // 0..3, wave-uniform
    const int   s  = tid & (S_SAMP - 1);
    const float sA = a * samples[s];

    float acc = 0.0f;
    const int i0 = (cnt * q) >> 2;
    const int i1 = (cnt * (q + 1)) >> 2;
    #pragma unroll 4
    for (int i = i0; i < i1; ++i) {
        const float4 v = pts[i];            // wave-uniform address -> LDS broadcast
        const float  d = sA - v.x;
        const float  u = fmaf(sgn, fabsf(d), v.y);   // -z*log2(e)
        const float  e = FAST_EXP2(u);               // 2^u
        acc = fmaf(v.z, FAST_RCP(1.0f + e), acc);    // w * sigmoid(z)
    }

    part[tid] = acc;
    __syncthreads();
    if (tid < S_SAMP) {
        const float rsum = part[tid] + part[tid + 128] + part[tid + 256] + part[tid + 384];
        out[(size_t)n * S_SAMP + tid] = rsum;
    }
}

extern "C" void kernel_launch(void* const* d_in, const int* in_sizes, int n_in,
                              void* d_out, int out_size, void* d_ws, size_t ws_size,
                              hipStream_t stream) {
    const float* diagrams = (const float*)d_in[0];
    const void*  mask     = d_in[1];
    const float* samples  = (const float*)d_in[2];
    const float* theta    = (const float*)d_in[3];
    const float* constant = (const float*)d_in[4];
    const float* power    = (const float*)d_in[5];
    float* out = (float*)d_out;

    const int N = in_sizes[0] / (2 * P_PTS);   // 512
    perslay_kernel<<<N, NTH, 0, stream>>>(diagrams, mask, samples, theta,
                                          constant, power, out);
}

// Round 3
// 92.070 us; speedup vs baseline: 1.0976x; 1.0976x over previous
//
#include <hip/hip_runtime.h>

#ifndef __has_builtin
#define __has_builtin(x) 0
#endif

#if __has_builtin(__builtin_amdgcn_exp2f)
#define FAST_EXP2(x) __builtin_amdgcn_exp2f(x)
#else
#define FAST_EXP2(x) exp2f(x)
#endif
#if __has_builtin(__builtin_amdgcn_rcpf)
#define FAST_RCP(x) __builtin_amdgcn_rcpf(x)
#else
#define FAST_RCP(x) (1.0f / (x))
#endif

#define P_PTS 2048   // points per diagram (problem constant)
#define S_SAMP 128   // samples (problem constant)
#define NTH 512      // threads per block
#define NG 32        // point streams (compacted index mod 32)
#define KS 8         // samples per thread: s = (tid&15) + 16*k

// One block per diagram n.
// Phase A: stage all 2048 points; per point pre-fold (A=2^(-c*y), B=2^(c*x), w)
//          where c = theta*log2(e); ballot-compact valid points into LDS.
// Phase C: thread (g = tid>>4, sbase = tid&15) sweeps stream g (compacted
//          indices == g mod 32) and accumulates KS=8 samples.  Per point-iter
//          per wave: ONE ds_read_b128 (4 contiguous addrs, conflict-free)
//          feeding 512 evals.  Eval: e^{-z} = max(E_s*A, B/E_s)  (c>=0),
//          term = w * rcp(1 + e^{-z})  ->  5 VALU + 1 trans, no exp in loop.
__global__ __launch_bounds__(NTH, 4) void perslay_kernel(
    const float* __restrict__ diagrams,   // (N, P, 2) f32
    const void*  __restrict__ maskp,      // (N, P) bool(byte) or int32 -- autodetected
    const float* __restrict__ samples,    // (S,) f32
    const float* __restrict__ theta,      // (1,)
    const float* __restrict__ constant,   // (1,)
    const float* __restrict__ power,      // (1,)
    float* __restrict__ out)              // (N, S) f32
{
    __shared__ float4 pts[P_PTS];   // compacted (A, B, w, 0); later aliased as part[]
    __shared__ int    woff[33];     // per-(round,wave) counts -> exclusive prefix

    const int n    = blockIdx.x;
    const int tid  = threadIdx.x;
    const int lane = tid & 63;
    const int wid  = tid >> 6;      // wave id 0..7

    const float th  = theta[0];
    const float cst = constant[0];
    const float pw  = power[0];
    const float c   = th * 1.4426950408889634f;   // theta * log2(e)

    // Mask dtype autodetect: byte-packed bool with valid-prefix -> word0=0x01010101.
    const unsigned int* mw = (const unsigned int*)maskp;
    const bool isByte = (mw[0] > 1u) | (mw[1] > 1u) | (mw[2] > 1u) | (mw[3] > 1u);

    const float2* __restrict__ dg = ((const float2*)diagrams) + (size_t)n * P_PTS;

    // ---- Phase A: stage + compact ------------------------------------------
    float4 val[4];
    int    rank[4];
    bool   valid[4];

    #pragma unroll
    for (int r = 0; r < 4; ++r) {
        const int p = r * NTH + tid;
        const float2 xy = dg[p];
        bool m;
        if (isByte) m = ((const unsigned char*)maskp)[(size_t)n * P_PTS + p] != 0;
        else        m = ((const int*)maskp)[(size_t)n * P_PTS + p] != 0;
        const float pers = xy.y - xy.x;
        const float ap   = fabsf(pers);
        float w;
        if (pw == 1.0f)      w = cst * ap;            // benchmark fast path
        else if (pw == 2.0f) w = cst * ap * ap;
        else                 w = cst * powf(ap, pw);
        valid[r] = m && (w != 0.0f);                  // zero-weight points add exactly 0
        const float A = FAST_EXP2(-c * xy.y);         // 2^(-c*y)
        const float B = FAST_EXP2( c * xy.x);         // 2^(+c*x)
        val[r] = make_float4(A, B, w, 0.0f);
        const unsigned long long b = __ballot(valid[r] ? 1 : 0);
        if (lane == 0) woff[r * 8 + wid] = (int)__popcll(b);
        rank[r] = (int)__popcll(b & ((1ull << lane) - 1ull));
    }
    __syncthreads();

    if (tid == 0) {  // exclusive prefix over the 32 (round,wave) chunks
        int run = 0;
        #pragma unroll
        for (int j = 0; j < 32; ++j) { const int t = woff[j]; woff[j] = run; run += t; }
        woff[32] = run;
    }
    __syncthreads();

    #pragma unroll
    for (int r = 0; r < 4; ++r)
        if (valid[r]) pts[woff[r * 8 + wid] + rank[r]] = val[r];
    const int cnt    = woff[32];                       // visible: written pre-barrier
    const int padded = (cnt + NG - 1) & ~(NG - 1);     // pad streams with w=0 entries
    if (tid < padded - cnt) pts[cnt + tid] = make_float4(0.0f, 0.0f, 0.0f, 0.0f);
    __syncthreads();

    // ---- Phase C: inner sweep ----------------------------------------------
    const int   g     = tid >> 4;          // stream 0..31
    const int   sbase = tid & 15;          // sample base

    float E[KS], rE[KS], acc[KS];
    #pragma unroll
    for (int k = 0; k < KS; ++k) {
        const float sv = samples[sbase + 16 * k];
        E[k]  = FAST_EXP2( c * sv);        // 2^(+c*s)
        rE[k] = FAST_EXP2(-c * sv);        // 2^(-c*s)
        acc[k] = 0.0f;
    }

    const int jmax = padded >> 5;          // padded / NG
    const float4* __restrict__ pbase = pts + g;

#define INNER_LOOP(SELFN)                                          \
    _Pragma("unroll 2")                                            \
    for (int j = 0; j < jmax; ++j) {                               \
        const float4 v = pbase[j * NG];                            \
        _Pragma("unroll")                                          \
        for (int k = 0; k < KS; ++k) {                             \
            const float t1 = E[k]  * v.x;                          \
            const float t2 = rE[k] * v.y;                          \
            const float u  = 1.0f + SELFN(t1, t2);                 \
            acc[k] = fmaf(v.z, FAST_RCP(u), acc[k]);               \
        }                                                          \
    }

    if (c >= 0.0f) { INNER_LOOP(fmaxf) } else { INNER_LOOP(fminf) }
#undef INNER_LOOP

    // ---- Reduction: 32 streams -> out[n, s] --------------------------------
    __syncthreads();                         // all reads of pts done -> safe to alias
    float* part = (float*)pts;               // [NG][S_SAMP] = 16 KB inside pts
    #pragma unroll
    for (int k = 0; k < KS; ++k)
        part[g * S_SAMP + sbase + 16 * k] = acc[k];
    __syncthreads();

    float* part2 = part + NG * S_SAMP;       // [4][S_SAMP], bytes 16K..18K of pts
    {
        const int s  = tid & (S_SAMP - 1);
        const int cq = tid >> 7;             // 0..3
        float t = 0.0f;
        #pragma unroll
        for (int gg = 0; gg < 8; ++gg)
            t += part[(cq * 8 + gg) * S_SAMP + s];
        part2[cq * S_SAMP + s] = t;
    }
    __syncthreads();

    if (tid < S_SAMP) {
        out[(size_t)n * S_SAMP + tid] =
            (part2[tid] + part2[S_SAMP + tid]) +
            (part2[2 * S_SAMP + tid] + part2[3 * S_SAMP + tid]);
    }
}

extern "C" void kernel_launch(void* const* d_in, const int* in_sizes, int n_in,
                              void* d_out, int out_size, void* d_ws, size_t ws_size,
                              hipStream_t stream) {
    const float* diagrams = (const float*)d_in[0];
    const void*  mask     = d_in[1];
    const float* samples  = (const float*)d_in[2];
    const float* theta    = (const float*)d_in[3];
    const float* constant = (const float*)d_in[4];
    const float* power    = (const float*)d_in[5];
    float* out = (float*)d_out;

    const int N = in_sizes[0] / (2 * P_PTS);   // 512
    perslay_kernel<<<N, NTH, 0, stream>>>(diagrams, mask, samples, theta,
                                          constant, power, out);
}